// Round 11
// baseline (413.565 us; speedup 1.0000x reference)
//
#include <hip/hip_runtime.h>
#include <hip/hip_bf16.h>
#include <math.h>

#define HID 128
#define HEADS 8
#define INDIM 64

typedef _Float16 f16x8 __attribute__((ext_vector_type(8)));
typedef _Float16 f16x4 __attribute__((ext_vector_type(4)));
typedef _Float16 f16x2 __attribute__((ext_vector_type(2)));
typedef float f32x4 __attribute__((ext_vector_type(4)));

__device__ __forceinline__ float fast_tanh(float x) {
    return 1.f - 2.f / (__expf(2.f * x) + 1.f);
}

#if defined(__has_builtin)
#if __has_builtin(__builtin_amdgcn_fdot2)
#define HAVE_FDOT2 1
#endif
#endif

// ================= fused prologue: count + convert_x + convert_w + gstart + hgZ zero ==========
__global__ void prologue_kernel(const int* __restrict__ ei, int* __restrict__ deg,
                                const float* __restrict__ x, _Float16* __restrict__ x16,
                                const float* __restrict__ emb_W, const float* __restrict__ gat_W,
                                const float* __restrict__ ga_W1, _Float16* __restrict__ wt_emb,
                                _Float16* __restrict__ wt_gat, _Float16* __restrict__ wt_ga1,
                                const int* __restrict__ batch, int* __restrict__ gstart,
                                float* __restrict__ hgZ,
                                int E, int EE, int N, int G, int XT4) {
    int i = blockIdx.x * blockDim.x + threadIdx.x;
    // x fp32 -> f16 (vector4)
    if (i < XT4) {
        float4 v = ((const float4*)x)[i];
        f16x4 o; o[0] = (_Float16)v.x; o[1] = (_Float16)v.y; o[2] = (_Float16)v.z; o[3] = (_Float16)v.w;
        *(f16x4*)&x16[4 * i] = o;
    }
    // degree histogram
    if (i < EE) {
        int dst = (i < E) ? ei[E + i] : (i - E);
        atomicAdd(&deg[dst], 1);
    }
    // weight transposes fp32 -> f16
    if (i < 8192) {                       // emb_W [64][128]
        int k = i >> 7, n = i & 127;
        wt_emb[n * 64 + k] = (_Float16)emb_W[i];
    } else if (i < 8192 + 49152) {        // gat_W [3][128][128]
        int j = i - 8192;
        int l = j >> 14, r = j & 16383;
        int k = r >> 7, n = r & 127;
        wt_gat[l * 16384 + n * 128 + k] = (_Float16)gat_W[j];
    } else if (i < 73728) {               // ga_W1 [128][128]
        int j = i - 57344;
        int k = j >> 7, n = j & 127;
        wt_ga1[n * 128 + k] = (_Float16)ga_W1[j];
    } else if (i < 73728 + 129) {         // hgZ zero
        hgZ[i - 73728] = 0.f;
    }
    // graph boundaries (batch sorted)
    if (i >= 100000 && i - 100000 <= G) {
        int g = i - 100000;
        int lo = 0, hi = N;
        while (lo < hi) {
            int mid = (lo + hi) >> 1;
            if (batch[mid] < g) lo = mid + 1; else hi = mid;
        }
        gstart[g] = lo;
    }
}

// ================= CSR scan chain =================
__global__ void block_sum_kernel(const int* __restrict__ deg, int* __restrict__ partials, int N) {
    __shared__ int sdata[4];
    int t = threadIdx.x;
    int i = blockIdx.x * 256 + t;
    int v = (i < N) ? deg[i] : 0;
#pragma unroll
    for (int m = 32; m >= 1; m >>= 1) v += __shfl_xor(v, m, 64);
    if ((t & 63) == 0) sdata[t >> 6] = v;
    __syncthreads();
    if (t == 0) partials[blockIdx.x] = sdata[0] + sdata[1] + sdata[2] + sdata[3];
}

// rowptr with integrated prefix over raw chunk sums (no separate scan_partials launch)
__global__ void rowptr_kernel(const int* __restrict__ deg, const int* __restrict__ partials,
                              int* __restrict__ rowptr, int* __restrict__ woff, int N, int EE) {
    __shared__ int tmp[256];
    __shared__ int red[4];
    int t = threadIdx.x;
    int b = blockIdx.x;
    // prefix = sum of partials[0..b)
    int p = 0;
    for (int i = t; i < b; i += 256) p += partials[i];
#pragma unroll
    for (int m = 32; m >= 1; m >>= 1) p += __shfl_xor(p, m, 64);
    if ((t & 63) == 0) red[t >> 6] = p;
    __syncthreads();
    int prefix = red[0] + red[1] + red[2] + red[3];
    int i = b * 256 + t;
    int v = (i < N) ? deg[i] : 0;
    tmp[t] = v;
    __syncthreads();
#pragma unroll
    for (int off = 1; off < 256; off <<= 1) {
        int x = (t >= off) ? tmp[t - off] : 0;
        __syncthreads();
        tmp[t] += x;
        __syncthreads();
    }
    int excl = tmp[t] - v + prefix;
    if (i < N) { rowptr[i] = excl; woff[i] = excl; }
    if (b == 0 && t == 0) rowptr[N] = EE;
}

__global__ void scatter_kernel(const int* __restrict__ ei, int* __restrict__ woff,
                               int* __restrict__ esrc, int E, int EE) {
    int e = blockIdx.x * blockDim.x + threadIdx.x;
    if (e >= EE) return;
    int src, dst;
    if (e < E) { src = ei[e]; dst = ei[E + e]; } else { src = dst = e - E; }
    int slot = atomicAdd(&woff[dst], 1);
    esrc[slot] = src;
}

// ================= unified MFMA projection kernel (1 row-tile per block) =================
// C[64 x 128] = A16[64 x K] @ W[K x 128]; A staged via LDS (coalesced).
// mode 0: embed epilogue (bias + ntype_emb -> h16)
// mode 1: GAT proj epilogue (hp16 store + als/ald via LDS transpose)
// mode 2: score epilogue (tanh MLP -> escore)
__global__ __launch_bounds__(256) void mfma_proj_kernel(
    int mode, int K, int N,
    const _Float16* __restrict__ A16, const _Float16* __restrict__ Wt,
    const float* __restrict__ bias, const float* __restrict__ nemb,
    const int* __restrict__ ntypes, _Float16* __restrict__ h16out,
    const float* __restrict__ asrc, const float* __restrict__ adst,
    _Float16* __restrict__ hp_out, float* __restrict__ als, float* __restrict__ ald,
    const float* __restrict__ w2, const float* __restrict__ b2,
    float* __restrict__ escore)
{
    __shared__ _Float16 w_lds[128 * 136];   // 34.8 KB
    __shared__ _Float16 a_lds[64 * 136];    // 17.4 KB
    int t = threadIdx.x;
    int n0 = blockIdx.x * 64;
    int KP = K + 8;
    int K8 = K >> 3;

    // stage W (coalesced)
    for (int i = t; i < 128 * K8; i += 256) {
        int row = i / K8, c8 = i - row * K8;
        *(f16x8*)&w_lds[row * KP + 8 * c8] = *(const f16x8*)&Wt[(size_t)row * K + 8 * c8];
    }
    // stage A (coalesced)
    for (int i = t; i < 64 * K8; i += 256) {
        int row = i / K8, c8 = i - row * K8;
        f16x8 v = {};
        if (n0 + row < N) v = *(const f16x8*)&A16[(size_t)(n0 + row) * K + 8 * c8];
        *(f16x8*)&a_lds[row * KP + 8 * c8] = v;
    }
    __syncthreads();

    int lane = t & 63, wv = t >> 6;
    int l15 = lane & 15, quad = lane >> 4;

    f32x4 acc[8];
#pragma unroll
    for (int c = 0; c < 8; ++c) acc[c] = (f32x4){0.f, 0.f, 0.f, 0.f};

    int ksteps = K >> 5;
    for (int kk = 0; kk < ksteps; ++kk) {
        f16x8 af = *(const f16x8*)&a_lds[(wv * 16 + l15) * KP + kk * 32 + quad * 8];
#pragma unroll
        for (int c = 0; c < 8; ++c) {
            f16x8 bf = *(const f16x8*)&w_lds[(c * 16 + l15) * KP + kk * 32 + quad * 8];
            acc[c] = __builtin_amdgcn_mfma_f32_16x16x32_f16(af, bf, acc[c], 0, 0, 0);
        }
    }

    // C layout: row = wv*16 + quad*4 + r, col = c*16 + l15
    if (mode == 0) {
        float bv[8];
#pragma unroll
        for (int c = 0; c < 8; ++c) bv[c] = bias[c * 16 + l15];
        __syncthreads();
#pragma unroll
        for (int r = 0; r < 4; ++r) {
            int n = n0 + wv * 16 + quad * 4 + r;
            int nt = (n < N) ? ntypes[n] : 0;
#pragma unroll
            for (int c = 0; c < 8; ++c)
                a_lds[(wv * 16 + quad * 4 + r) * 136 + c * 16 + l15] =
                    (_Float16)(acc[c][r] + bv[c] + nemb[nt * HID + c * 16 + l15]);
        }
        __syncthreads();
        for (int i = t; i < 64 * 16; i += 256) {
            int row = i >> 4, c8 = i & 15;
            int n = n0 + row;
            if (n < N) *(f16x8*)&h16out[(size_t)n * HID + 8 * c8] = *(const f16x8*)&a_lds[row * 136 + 8 * c8];
        }
    } else if (mode == 1) {
        __syncthreads();
#pragma unroll
        for (int c = 0; c < 8; ++c)
#pragma unroll
            for (int r = 0; r < 4; ++r)
                a_lds[(wv * 16 + quad * 4 + r) * 136 + c * 16 + l15] = (_Float16)acc[c][r];
        __syncthreads();
        // hp16 store (coalesced 16B)
        for (int i = t; i < 64 * 16; i += 256) {
            int row = i >> 4, c8 = i & 15;
            int n = n0 + row;
            if (n < N) *(f16x8*)&hp_out[(size_t)n * HID + 8 * c8] = *(const f16x8*)&a_lds[row * 136 + 8 * c8];
        }
        // als/ald from LDS transpose: task = row*8 + head
        for (int task = t; task < 512; task += 256) {
            int row = task >> 3, hd = task & 7;
            int n = n0 + row;
            if (n >= N) continue;
            f16x8 v0 = *(const f16x8*)&a_lds[row * 136 + hd * 16];
            f16x8 v1 = *(const f16x8*)&a_lds[row * 136 + hd * 16 + 8];
            float va = 0.f, vd = 0.f;
#pragma unroll
            for (int j = 0; j < 8; ++j) {
                va += (float)v0[j] * asrc[hd * 16 + j] + (float)v1[j] * asrc[hd * 16 + 8 + j];
                vd += (float)v0[j] * adst[hd * 16 + j] + (float)v1[j] * adst[hd * 16 + 8 + j];
            }
            als[n * HEADS + hd] = va;
            ald[n * HEADS + hd] = vd;
        }
    } else {
        float b2v = b2[0];
        float treg[4] = {0.f, 0.f, 0.f, 0.f};
#pragma unroll
        for (int c = 0; c < 8; ++c) {
            float b1v = bias[c * 16 + l15];
            float w2v = w2[c * 16 + l15];
#pragma unroll
            for (int r = 0; r < 4; ++r)
                treg[r] += fast_tanh(acc[c][r] + b1v) * w2v;
        }
#pragma unroll
        for (int r = 0; r < 4; ++r) {
            float v = treg[r];
#pragma unroll
            for (int m = 8; m >= 1; m >>= 1) v += __shfl_xor(v, m, 64);
            if (l15 == 0) {
                int n = n0 + wv * 16 + quad * 4 + r;
                if (n < N) escore[n] = __expf(v + b2v);
            }
        }
    }
}

// ================= fused aggregate: 16 edges in flight, esrc prefetch, packed fdot2 ==========
// lane = (edge-sub 0..3, chan-grp 0..15); each lane gathers 4x f16x8 per iteration.
__global__ void gat_aggregate_kernel(const int* __restrict__ rowptr, const int* __restrict__ esrc,
                                     const float* __restrict__ als, const float* __restrict__ ald,
                                     const _Float16* __restrict__ hp16, const float* __restrict__ gb,
                                     const float* __restrict__ lg, const float* __restrict__ lb,
                                     _Float16* __restrict__ h16, int N) {
    int wave = threadIdx.x >> 6;
    int lane = threadIdx.x & 63;
    int n = blockIdx.x * 4 + wave;
    if (n >= N) return;
    int esub = lane >> 4;          // 0..3
    int cg = lane & 15;            // channels cg*8 .. cg*8+7 (head cg>>1)
    int hd = cg >> 1;
    float adv = ald[n * HEADS + hd];
    int row = rowptr[n], end = rowptr[n + 1];   // end > row (self-loop)
    int last = end - 1;
    float acc[8] = {0.f, 0.f, 0.f, 0.f, 0.f, 0.f, 0.f, 0.f};
    float sw = 0.f;
    // prefetch first iteration's src indices
    int jA = row + esub;           int sA_n = esrc[jA <= last ? jA : last];
    int jB = jA + 4;               int sB_n = esrc[jB <= last ? jB : last];
    int jC = jA + 8;               int sC_n = esrc[jC <= last ? jC : last];
    int jD = jA + 12;              int sD_n = esrc[jD <= last ? jD : last];
    for (int base = row; base < end; base += 16) {
        int sA = sA_n, sB = sB_n, sC = sC_n, sD = sD_n;
        int iA = base + esub;
        if (base + 16 < end) {
            int kA = iA + 16;
            int kB = kA + 4, kC = kA + 8, kD = kA + 12;
            sA_n = esrc[kA <= last ? kA : last];
            sB_n = esrc[kB <= last ? kB : last];
            sC_n = esrc[kC <= last ? kC : last];
            sD_n = esrc[kD <= last ? kD : last];
        }
        f16x8 pA = *(const f16x8*)&hp16[(size_t)sA * HID + cg * 8];
        f16x8 pB = *(const f16x8*)&hp16[(size_t)sB * HID + cg * 8];
        f16x8 pC = *(const f16x8*)&hp16[(size_t)sC * HID + cg * 8];
        f16x8 pD = *(const f16x8*)&hp16[(size_t)sD * HID + cg * 8];
        float aA = als[sA * HEADS + hd];
        float aB = als[sB * HEADS + hd];
        float aC = als[sC * HEADS + hd];
        float aD = als[sD * HEADS + hd];
        float lA = aA + adv; lA = lA > 0.f ? lA : 0.2f * lA;
        float lB = aB + adv; lB = lB > 0.f ? lB : 0.2f * lB;
        float lC = aC + adv; lC = lC > 0.f ? lC : 0.2f * lC;
        float lD = aD + adv; lD = lD > 0.f ? lD : 0.2f * lD;
        float wA = __expf(lA) * ((iA < end) ? 1.f : 0.f);
        float wB = __expf(lB) * ((iA + 4 < end) ? 1.f : 0.f);
        float wC = __expf(lC) * ((iA + 8 < end) ? 1.f : 0.f);
        float wD = __expf(lD) * ((iA + 12 < end) ? 1.f : 0.f);
        sw += (wA + wB) + (wC + wD);
#ifdef HAVE_FDOT2
        f16x2 wAB; wAB[0] = (_Float16)wA; wAB[1] = (_Float16)wB;
        f16x2 wCD; wCD[0] = (_Float16)wC; wCD[1] = (_Float16)wD;
#pragma unroll
        for (int j = 0; j < 8; ++j) {
            f16x2 prAB; prAB[0] = pA[j]; prAB[1] = pB[j];
            f16x2 prCD; prCD[0] = pC[j]; prCD[1] = pD[j];
            acc[j] = __builtin_amdgcn_fdot2(prAB, wAB, acc[j], false);
            acc[j] = __builtin_amdgcn_fdot2(prCD, wCD, acc[j], false);
        }
#else
#pragma unroll
        for (int j = 0; j < 8; ++j)
            acc[j] += wA * (float)pA[j] + wB * (float)pB[j]
                    + wC * (float)pC[j] + wD * (float)pD[j];
#endif
    }
    // combine the 4 edge-subgroups (lane bits 4,5)
#pragma unroll
    for (int m = 16; m <= 32; m <<= 1) {
        sw += __shfl_xor(sw, m, 64);
#pragma unroll
        for (int j = 0; j < 8; ++j) acc[j] += __shfl_xor(acc[j], m, 64);
    }
    float inv_sw = 1.f / sw;
    float4 g0 = ((const float4*)(gb + cg * 8))[0];
    float4 g1 = ((const float4*)(gb + cg * 8))[1];
    float v[8];
    v[0] = acc[0] * inv_sw + g0.x; v[1] = acc[1] * inv_sw + g0.y;
    v[2] = acc[2] * inv_sw + g0.z; v[3] = acc[3] * inv_sw + g0.w;
    v[4] = acc[4] * inv_sw + g1.x; v[5] = acc[5] * inv_sw + g1.y;
    v[6] = acc[6] * inv_sw + g1.z; v[7] = acc[7] * inv_sw + g1.w;
    // layernorm: each channel appears 4x across the wave -> /512
    float s = 0.f;
#pragma unroll
    for (int j = 0; j < 8; ++j) s += v[j];
#pragma unroll
    for (int m = 32; m >= 1; m >>= 1) s += __shfl_xor(s, m, 64);
    float mu = s * (1.f / 512.f);
    float d[8], sq = 0.f;
#pragma unroll
    for (int j = 0; j < 8; ++j) { d[j] = v[j] - mu; sq += d[j] * d[j]; }
#pragma unroll
    for (int m = 32; m >= 1; m >>= 1) sq += __shfl_xor(sq, m, 64);
    float inv = rsqrtf(sq * (1.f / 512.f) + 1e-5f);
    float4 lg0 = ((const float4*)(lg + cg * 8))[0];
    float4 lg1 = ((const float4*)(lg + cg * 8))[1];
    float4 lb0 = ((const float4*)(lb + cg * 8))[0];
    float4 lb1 = ((const float4*)(lb + cg * 8))[1];
    float lgv[8] = {lg0.x, lg0.y, lg0.z, lg0.w, lg1.x, lg1.y, lg1.z, lg1.w};
    float lbv[8] = {lb0.x, lb0.y, lb0.z, lb0.w, lb1.x, lb1.y, lb1.z, lb1.w};
    f16x8 hold = *(const f16x8*)&h16[(size_t)n * HID + cg * 8];
    f16x8 hnew;
#pragma unroll
    for (int j = 0; j < 8; ++j) {
        float r = d[j] * inv * lgv[j] + lbv[j] + (float)hold[j];
        hnew[j] = (_Float16)(r > 0.f ? r : 0.f);
    }
    if (esub == 0) *(f16x8*)&h16[(size_t)n * HID + cg * 8] = hnew;
}

// ================= per-graph pooling (h16) =================
__global__ void pool_graph_kernel(const _Float16* __restrict__ h16, const float* __restrict__ escore,
                                  const int* __restrict__ gstart, float* __restrict__ sums,
                                  float* __restrict__ cnts, float* __restrict__ hgZ, int G) {
    int g = blockIdx.x;
    int t = threadIdx.x;               // 0..511
    int c = t & 127, grp = t >> 7;     // 4 groups
    int s = gstart[g], e = gstart[g + 1];
    float msum = 0.f, asum = 0.f, z = 0.f;
    for (int n = s + grp; n < e; n += 4) {
        float hv = (float)h16[(size_t)n * HID + c];
        float es = escore[n];
        msum += hv;
        asum += es * hv;
        if (c == 0) z += es;
    }
    __shared__ float sm[4][HID];
    __shared__ float sa[4][HID];
    __shared__ float sz[4];
    sm[grp][c] = msum;
    sa[grp][c] = asum;
    if (c == 0) sz[grp] = z;
    __syncthreads();
    if (t < HID) {
        float m = sm[0][t] + sm[1][t] + sm[2][t] + sm[3][t];
        float a = sa[0][t] + sa[1][t] + sa[2][t] + sa[3][t];
        sums[(size_t)g * HID + t] = m;
        atomicAdd(&hgZ[t], a);
    } else if (t == HID) {
        cnts[g] = (float)(e - s);
        atomicAdd(&hgZ[HID], sz[0] + sz[1] + sz[2] + sz[3]);
    }
}

// ================= classifier head =================
__global__ void head_kernel(const float* __restrict__ hgZ, const float* __restrict__ sums,
                            const float* __restrict__ cnts, const float* __restrict__ W1,
                            const float* __restrict__ b1, const float* __restrict__ W2,
                            const float* __restrict__ b2, float* __restrict__ out, int G) {
    int g = blockIdx.x;
    int t = threadIdx.x;
    __shared__ float hr[HID];
    __shared__ float part[2];
    float Z = hgZ[HID];
    float cnt = cnts[g];
    cnt = cnt > 1.f ? cnt : 1.f;
    hr[t] = hgZ[t] / Z + sums[(size_t)g * HID + t] / cnt;
    __syncthreads();
    float acc = b1[t];
#pragma unroll 8
    for (int k = 0; k < HID; ++k) acc += hr[k] * W1[k * HID + t];
    acc = acc > 0.f ? acc : 0.f;
    float v = acc * W2[t];
#pragma unroll
    for (int m = 32; m >= 1; m >>= 1) v += __shfl_xor(v, m, 64);
    if ((t & 63) == 0) part[t >> 6] = v;
    __syncthreads();
    if (t == 0) out[g] = part[0] + part[1] + b2[0];
}

extern "C" void kernel_launch(void* const* d_in, const int* in_sizes, int n_in,
                              void* d_out, int out_size, void* d_ws, size_t ws_size,
                              hipStream_t stream) {
    const float* x        = (const float*)d_in[0];
    const int*   ei       = (const int*)d_in[1];
    const int*   ntypes   = (const int*)d_in[2];
    const int*   batch    = (const int*)d_in[3];
    const float* emb_W    = (const float*)d_in[4];
    const float* emb_b    = (const float*)d_in[5];
    const float* nemb     = (const float*)d_in[6];
    const float* gat_W    = (const float*)d_in[7];
    const float* att_src  = (const float*)d_in[8];
    const float* att_dst  = (const float*)d_in[9];
    const float* gat_b    = (const float*)d_in[10];
    const float* ln_g     = (const float*)d_in[11];
    const float* ln_b     = (const float*)d_in[12];
    const float* ga_W1    = (const float*)d_in[13];
    const float* ga_b1    = (const float*)d_in[14];
    const float* ga_W2    = (const float*)d_in[15];
    const float* ga_b2    = (const float*)d_in[16];
    const float* cls_W1   = (const float*)d_in[17];
    const float* cls_b1   = (const float*)d_in[18];
    const float* cls_W2   = (const float*)d_in[19];
    const float* cls_b2   = (const float*)d_in[20];
    float* out = (float*)d_out;

    const int N  = in_sizes[2];
    const int E  = in_sizes[1] / 2;
    const int EE = E + N;
    const int G  = out_size;
    const int NB = (N + 255) / 256;
    const int XT4 = N * INDIM / 4;

    float* ws      = (float*)d_ws;
    float* als     = ws;                               // N*8
    float* ald     = als + (size_t)N * HEADS;          // N*8
    float* escore  = ald + (size_t)N * HEADS;          // N
    float* sums    = escore + N;                       // G*128
    float* cnts    = sums + (size_t)G * HID;           // G
    float* hgZ     = cnts + G;                         // 129
    _Float16* h16  = (_Float16*)(hgZ + HID + 1);       // N*128
    _Float16* hp16 = h16 + (size_t)N * HID;            // N*128
    _Float16* x16  = hp16 + (size_t)N * HID;           // N*64
    _Float16* wt_emb = x16 + (size_t)N * INDIM;        // 128*64
    _Float16* wt_gat = wt_emb + 128 * 64;              // 3*128*128
    _Float16* wt_ga1 = wt_gat + 3 * 128 * 128;         // 128*128
    int*   rowptr  = (int*)(wt_ga1 + 128 * 128);       // N+1
    int*   woff    = rowptr + (N + 1);                 // N
    int*   deg     = woff + N;                         // N
    int*   esrc    = deg + N;                          // EE
    int*   partials= esrc + EE;                        // NB
    int*   gstart  = partials + NB;                    // G+1

    // ---- prologue: deg zero, then fused count/converts/gstart/hgZ-zero ----
    hipMemsetAsync(deg, 0, (size_t)N * sizeof(int), stream);
    int ptot = XT4 > EE ? XT4 : EE;
    if (ptot < 100000 + G + 1) ptot = 100000 + G + 1;
    prologue_kernel<<<(ptot + 255) / 256, 256, 0, stream>>>(
        ei, deg, x, x16, emb_W, gat_W, ga_W1, wt_emb, wt_gat, wt_ga1,
        batch, gstart, hgZ, E, EE, N, G, XT4);
    block_sum_kernel<<<NB, 256, 0, stream>>>(deg, partials, N);
    rowptr_kernel<<<NB, 256, 0, stream>>>(deg, partials, rowptr, woff, N, EE);
    scatter_kernel<<<(EE + 255) / 256, 256, 0, stream>>>(ei, woff, esrc, E, EE);

    const int PB = (N + 63) / 64;

    // ---- network ----
    mfma_proj_kernel<<<PB, 256, 0, stream>>>(
        0, INDIM, N, x16, wt_emb, emb_b, nemb, ntypes, h16,
        nullptr, nullptr, nullptr, nullptr, nullptr, nullptr, nullptr, nullptr);

    for (int l = 0; l < 3; ++l) {
        mfma_proj_kernel<<<PB, 256, 0, stream>>>(
            1, HID, N, h16, wt_gat + (size_t)l * HID * HID,
            nullptr, nullptr, nullptr, nullptr,
            att_src + l * HID, att_dst + l * HID,
            hp16, als, ald, nullptr, nullptr, nullptr);
        gat_aggregate_kernel<<<(N + 3) / 4, 256, 0, stream>>>(
            rowptr, esrc, als, ald, hp16,
            gat_b + l * HID, ln_g + l * HID, ln_b + l * HID, h16, N);
    }

    mfma_proj_kernel<<<PB, 256, 0, stream>>>(
        2, HID, N, h16, wt_ga1, ga_b1, nullptr, nullptr, nullptr,
        nullptr, nullptr, nullptr, nullptr, nullptr, ga_W2, ga_b2, escore);

    pool_graph_kernel<<<G, 512, 0, stream>>>(h16, escore, gstart, sums, cnts, hgZ, G);
    head_kernel<<<G, 128, 0, stream>>>(hgZ, sums, cnts, cls_W1, cls_b1, cls_W2, cls_b2, out, G);
}

// Round 12
// 406.476 us; speedup vs baseline: 1.0174x; 1.0174x over previous
//
#include <hip/hip_runtime.h>
#include <hip/hip_bf16.h>
#include <math.h>

#define HID 128
#define HEADS 8
#define INDIM 64

typedef _Float16 f16x8 __attribute__((ext_vector_type(8)));
typedef _Float16 f16x4 __attribute__((ext_vector_type(4)));
typedef _Float16 f16x2 __attribute__((ext_vector_type(2)));
typedef float f32x4 __attribute__((ext_vector_type(4)));

__device__ __forceinline__ float fast_tanh(float x) {
    return 1.f - 2.f / (__expf(2.f * x) + 1.f);
}

#if defined(__has_builtin)
#if __has_builtin(__builtin_amdgcn_fdot2)
#define HAVE_FDOT2 1
#endif
#endif

// ================= fused prologue: count + convert_x + convert_w + gstart + hgZ zero ==========
__global__ void prologue_kernel(const int* __restrict__ ei, int* __restrict__ deg,
                                const float* __restrict__ x, _Float16* __restrict__ x16,
                                const float* __restrict__ emb_W, const float* __restrict__ gat_W,
                                const float* __restrict__ ga_W1, _Float16* __restrict__ wt_emb,
                                _Float16* __restrict__ wt_gat, _Float16* __restrict__ wt_ga1,
                                const int* __restrict__ batch, int* __restrict__ gstart,
                                float* __restrict__ hgZ,
                                int E, int EE, int N, int G, int XT4) {
    int i = blockIdx.x * blockDim.x + threadIdx.x;
    // x fp32 -> f16 (vector4)
    if (i < XT4) {
        float4 v = ((const float4*)x)[i];
        f16x4 o; o[0] = (_Float16)v.x; o[1] = (_Float16)v.y; o[2] = (_Float16)v.z; o[3] = (_Float16)v.w;
        *(f16x4*)&x16[4 * i] = o;
    }
    // degree histogram
    if (i < EE) {
        int dst = (i < E) ? ei[E + i] : (i - E);
        atomicAdd(&deg[dst], 1);
    }
    // weight transposes fp32 -> f16
    if (i < 8192) {                       // emb_W [64][128]
        int k = i >> 7, n = i & 127;
        wt_emb[n * 64 + k] = (_Float16)emb_W[i];
    } else if (i < 8192 + 49152) {        // gat_W [3][128][128]
        int j = i - 8192;
        int l = j >> 14, r = j & 16383;
        int k = r >> 7, n = r & 127;
        wt_gat[l * 16384 + n * 128 + k] = (_Float16)gat_W[j];
    } else if (i < 73728) {               // ga_W1 [128][128]
        int j = i - 57344;
        int k = j >> 7, n = j & 127;
        wt_ga1[n * 128 + k] = (_Float16)ga_W1[j];
    } else if (i < 73728 + 129) {         // hgZ zero
        hgZ[i - 73728] = 0.f;
    }
    // graph boundaries (batch sorted)
    if (i >= 100000 && i - 100000 <= G) {
        int g = i - 100000;
        int lo = 0, hi = N;
        while (lo < hi) {
            int mid = (lo + hi) >> 1;
            if (batch[mid] < g) lo = mid + 1; else hi = mid;
        }
        gstart[g] = lo;
    }
}

// ================= CSR scan chain =================
__global__ void block_sum_kernel(const int* __restrict__ deg, int* __restrict__ partials, int N) {
    __shared__ int sdata[4];
    int t = threadIdx.x;
    int i = blockIdx.x * 256 + t;
    int v = (i < N) ? deg[i] : 0;
#pragma unroll
    for (int m = 32; m >= 1; m >>= 1) v += __shfl_xor(v, m, 64);
    if ((t & 63) == 0) sdata[t >> 6] = v;
    __syncthreads();
    if (t == 0) partials[blockIdx.x] = sdata[0] + sdata[1] + sdata[2] + sdata[3];
}

// rowptr with integrated prefix over raw chunk sums (no separate scan_partials launch)
__global__ void rowptr_kernel(const int* __restrict__ deg, const int* __restrict__ partials,
                              int* __restrict__ rowptr, int* __restrict__ woff, int N, int EE) {
    __shared__ int tmp[256];
    __shared__ int red[4];
    int t = threadIdx.x;
    int b = blockIdx.x;
    // prefix = sum of partials[0..b)
    int p = 0;
    for (int i = t; i < b; i += 256) p += partials[i];
#pragma unroll
    for (int m = 32; m >= 1; m >>= 1) p += __shfl_xor(p, m, 64);
    if ((t & 63) == 0) red[t >> 6] = p;
    __syncthreads();
    int prefix = red[0] + red[1] + red[2] + red[3];
    int i = b * 256 + t;
    int v = (i < N) ? deg[i] : 0;
    tmp[t] = v;
    __syncthreads();
#pragma unroll
    for (int off = 1; off < 256; off <<= 1) {
        int x = (t >= off) ? tmp[t - off] : 0;
        __syncthreads();
        tmp[t] += x;
        __syncthreads();
    }
    int excl = tmp[t] - v + prefix;
    if (i < N) { rowptr[i] = excl; woff[i] = excl; }
    if (b == 0 && t == 0) rowptr[N] = EE;
}

__global__ void scatter_kernel(const int* __restrict__ ei, int* __restrict__ woff,
                               int* __restrict__ esrc, int E, int EE) {
    int e = blockIdx.x * blockDim.x + threadIdx.x;
    if (e >= EE) return;
    int src, dst;
    if (e < E) { src = ei[e]; dst = ei[E + e]; } else { src = dst = e - E; }
    int slot = atomicAdd(&woff[dst], 1);
    esrc[slot] = src;
}

// ================= unified MFMA projection kernel (2 row-tiles per block) =================
// C[64 x 128] = A16[64 x K] @ W[K x 128]; A staged via LDS (coalesced); W staged once.
// mode 0: embed epilogue (bias + ntype_emb -> h16)
// mode 1: GAT proj epilogue (hp16 store + als/ald via LDS transpose)
// mode 2: score epilogue (tanh MLP -> escore)
__global__ __launch_bounds__(256) void mfma_proj_kernel(
    int mode, int K, int N,
    const _Float16* __restrict__ A16, const _Float16* __restrict__ Wt,
    const float* __restrict__ bias, const float* __restrict__ nemb,
    const int* __restrict__ ntypes, _Float16* __restrict__ h16out,
    const float* __restrict__ asrc, const float* __restrict__ adst,
    _Float16* __restrict__ hp_out, float* __restrict__ als, float* __restrict__ ald,
    const float* __restrict__ w2, const float* __restrict__ b2,
    float* __restrict__ escore)
{
    __shared__ _Float16 w_lds[128 * 136];   // 34.8 KB
    __shared__ _Float16 a_lds[64 * 136];    // 17.4 KB
    int t = threadIdx.x;
    int KP = K + 8;
    int K8 = K >> 3;

    // stage W once (coalesced)
    for (int i = t; i < 128 * K8; i += 256) {
        int row = i / K8, c8 = i - row * K8;
        *(f16x8*)&w_lds[row * KP + 8 * c8] = *(const f16x8*)&Wt[(size_t)row * K + 8 * c8];
    }

    int lane = t & 63, wv = t >> 6;
    int l15 = lane & 15, quad = lane >> 4;

    for (int tile = 0; tile < 2; ++tile) {
        int n0 = blockIdx.x * 128 + tile * 64;
        if (n0 >= N) break;
        __syncthreads();   // W ready (tile 0) / previous epilogue done with a_lds
        // stage A (coalesced)
        for (int i = t; i < 64 * K8; i += 256) {
            int row = i / K8, c8 = i - row * K8;
            f16x8 v = {};
            if (n0 + row < N) v = *(const f16x8*)&A16[(size_t)(n0 + row) * K + 8 * c8];
            *(f16x8*)&a_lds[row * KP + 8 * c8] = v;
        }
        __syncthreads();

        f32x4 acc[8];
#pragma unroll
        for (int c = 0; c < 8; ++c) acc[c] = (f32x4){0.f, 0.f, 0.f, 0.f};

        int ksteps = K >> 5;
        for (int kk = 0; kk < ksteps; ++kk) {
            f16x8 af = *(const f16x8*)&a_lds[(wv * 16 + l15) * KP + kk * 32 + quad * 8];
#pragma unroll
            for (int c = 0; c < 8; ++c) {
                f16x8 bf = *(const f16x8*)&w_lds[(c * 16 + l15) * KP + kk * 32 + quad * 8];
                acc[c] = __builtin_amdgcn_mfma_f32_16x16x32_f16(af, bf, acc[c], 0, 0, 0);
            }
        }

        // C layout: row = wv*16 + quad*4 + r, col = c*16 + l15
        if (mode == 0) {
            float bv[8];
#pragma unroll
            for (int c = 0; c < 8; ++c) bv[c] = bias[c * 16 + l15];
            __syncthreads();
#pragma unroll
            for (int r = 0; r < 4; ++r) {
                int n = n0 + wv * 16 + quad * 4 + r;
                int nt = (n < N) ? ntypes[n] : 0;
#pragma unroll
                for (int c = 0; c < 8; ++c)
                    a_lds[(wv * 16 + quad * 4 + r) * 136 + c * 16 + l15] =
                        (_Float16)(acc[c][r] + bv[c] + nemb[nt * HID + c * 16 + l15]);
            }
            __syncthreads();
            for (int i = t; i < 64 * 16; i += 256) {
                int row = i >> 4, c8 = i & 15;
                int n = n0 + row;
                if (n < N) *(f16x8*)&h16out[(size_t)n * HID + 8 * c8] = *(const f16x8*)&a_lds[row * 136 + 8 * c8];
            }
        } else if (mode == 1) {
            __syncthreads();
#pragma unroll
            for (int c = 0; c < 8; ++c)
#pragma unroll
                for (int r = 0; r < 4; ++r)
                    a_lds[(wv * 16 + quad * 4 + r) * 136 + c * 16 + l15] = (_Float16)acc[c][r];
            __syncthreads();
            // hp16 store (coalesced 16B)
            for (int i = t; i < 64 * 16; i += 256) {
                int row = i >> 4, c8 = i & 15;
                int n = n0 + row;
                if (n < N) *(f16x8*)&hp_out[(size_t)n * HID + 8 * c8] = *(const f16x8*)&a_lds[row * 136 + 8 * c8];
            }
            // als/ald from LDS transpose: task = row*8 + head
            for (int task = t; task < 512; task += 256) {
                int row = task >> 3, hd = task & 7;
                int n = n0 + row;
                if (n >= N) continue;
                f16x8 v0 = *(const f16x8*)&a_lds[row * 136 + hd * 16];
                f16x8 v1 = *(const f16x8*)&a_lds[row * 136 + hd * 16 + 8];
                float va = 0.f, vd = 0.f;
#pragma unroll
                for (int j = 0; j < 8; ++j) {
                    va += (float)v0[j] * asrc[hd * 16 + j] + (float)v1[j] * asrc[hd * 16 + 8 + j];
                    vd += (float)v0[j] * adst[hd * 16 + j] + (float)v1[j] * adst[hd * 16 + 8 + j];
                }
                als[n * HEADS + hd] = va;
                ald[n * HEADS + hd] = vd;
            }
        } else {
            float b2v = b2[0];
            float treg[4] = {0.f, 0.f, 0.f, 0.f};
#pragma unroll
            for (int c = 0; c < 8; ++c) {
                float b1v = bias[c * 16 + l15];
                float w2v = w2[c * 16 + l15];
#pragma unroll
                for (int r = 0; r < 4; ++r)
                    treg[r] += fast_tanh(acc[c][r] + b1v) * w2v;
            }
#pragma unroll
            for (int r = 0; r < 4; ++r) {
                float v = treg[r];
#pragma unroll
                for (int m = 8; m >= 1; m >>= 1) v += __shfl_xor(v, m, 64);
                if (l15 == 0) {
                    int n = n0 + wv * 16 + quad * 4 + r;
                    if (n < N) escore[n] = __expf(v + b2v);
                }
            }
        }
    }
}

// ================= fused aggregate: 16 edges in flight, packed fdot2 =================
// lane = (edge-sub 0..3, chan-grp 0..15); each lane gathers 4x f16x8 per iteration.
__global__ void gat_aggregate_kernel(const int* __restrict__ rowptr, const int* __restrict__ esrc,
                                     const float* __restrict__ als, const float* __restrict__ ald,
                                     const _Float16* __restrict__ hp16, const float* __restrict__ gb,
                                     const float* __restrict__ lg, const float* __restrict__ lb,
                                     _Float16* __restrict__ h16, int N) {
    int wave = threadIdx.x >> 6;
    int lane = threadIdx.x & 63;
    int n = blockIdx.x * 4 + wave;
    if (n >= N) return;
    int esub = lane >> 4;          // 0..3
    int cg = lane & 15;            // channels cg*8 .. cg*8+7 (head cg>>1)
    int hd = cg >> 1;
    float adv = ald[n * HEADS + hd];
    int row = rowptr[n], end = rowptr[n + 1];   // end > row (self-loop)
    int last = end - 1;
    float acc[8] = {0.f, 0.f, 0.f, 0.f, 0.f, 0.f, 0.f, 0.f};
    float sw = 0.f;
    for (int base = row; base < end; base += 16) {
        int iA = base + esub;
        int iB = iA + 4, iC = iA + 8, iD = iA + 12;
        int cA = iA <= last ? iA : last;
        int cB = iB <= last ? iB : last;
        int cC = iC <= last ? iC : last;
        int cD = iD <= last ? iD : last;
        int sA = esrc[cA], sB = esrc[cB], sC = esrc[cC], sD = esrc[cD];
        f16x8 pA = *(const f16x8*)&hp16[(size_t)sA * HID + cg * 8];
        f16x8 pB = *(const f16x8*)&hp16[(size_t)sB * HID + cg * 8];
        f16x8 pC = *(const f16x8*)&hp16[(size_t)sC * HID + cg * 8];
        f16x8 pD = *(const f16x8*)&hp16[(size_t)sD * HID + cg * 8];
        float aA = als[sA * HEADS + hd];
        float aB = als[sB * HEADS + hd];
        float aC = als[sC * HEADS + hd];
        float aD = als[sD * HEADS + hd];
        float lA = aA + adv; lA = lA > 0.f ? lA : 0.2f * lA;
        float lB = aB + adv; lB = lB > 0.f ? lB : 0.2f * lB;
        float lC = aC + adv; lC = lC > 0.f ? lC : 0.2f * lC;
        float lD = aD + adv; lD = lD > 0.f ? lD : 0.2f * lD;
        float wA = __expf(lA) * ((iA < end) ? 1.f : 0.f);
        float wB = __expf(lB) * ((iB < end) ? 1.f : 0.f);
        float wC = __expf(lC) * ((iC < end) ? 1.f : 0.f);
        float wD = __expf(lD) * ((iD < end) ? 1.f : 0.f);
        sw += (wA + wB) + (wC + wD);
#ifdef HAVE_FDOT2
        f16x2 wAB; wAB[0] = (_Float16)wA; wAB[1] = (_Float16)wB;
        f16x2 wCD; wCD[0] = (_Float16)wC; wCD[1] = (_Float16)wD;
#pragma unroll
        for (int j = 0; j < 8; ++j) {
            f16x2 prAB; prAB[0] = pA[j]; prAB[1] = pB[j];
            f16x2 prCD; prCD[0] = pC[j]; prCD[1] = pD[j];
            acc[j] = __builtin_amdgcn_fdot2(prAB, wAB, acc[j], false);
            acc[j] = __builtin_amdgcn_fdot2(prCD, wCD, acc[j], false);
        }
#else
#pragma unroll
        for (int j = 0; j < 8; ++j)
            acc[j] += wA * (float)pA[j] + wB * (float)pB[j]
                    + wC * (float)pC[j] + wD * (float)pD[j];
#endif
    }
    // combine the 4 edge-subgroups (lane bits 4,5)
#pragma unroll
    for (int m = 16; m <= 32; m <<= 1) {
        sw += __shfl_xor(sw, m, 64);
#pragma unroll
        for (int j = 0; j < 8; ++j) acc[j] += __shfl_xor(acc[j], m, 64);
    }
    float inv_sw = 1.f / sw;
    float4 g0 = ((const float4*)(gb + cg * 8))[0];
    float4 g1 = ((const float4*)(gb + cg * 8))[1];
    float v[8];
    v[0] = acc[0] * inv_sw + g0.x; v[1] = acc[1] * inv_sw + g0.y;
    v[2] = acc[2] * inv_sw + g0.z; v[3] = acc[3] * inv_sw + g0.w;
    v[4] = acc[4] * inv_sw + g1.x; v[5] = acc[5] * inv_sw + g1.y;
    v[6] = acc[6] * inv_sw + g1.z; v[7] = acc[7] * inv_sw + g1.w;
    // layernorm: each channel appears 4x across the wave -> /512
    float s = 0.f;
#pragma unroll
    for (int j = 0; j < 8; ++j) s += v[j];
#pragma unroll
    for (int m = 32; m >= 1; m >>= 1) s += __shfl_xor(s, m, 64);
    float mu = s * (1.f / 512.f);
    float d[8], sq = 0.f;
#pragma unroll
    for (int j = 0; j < 8; ++j) { d[j] = v[j] - mu; sq += d[j] * d[j]; }
#pragma unroll
    for (int m = 32; m >= 1; m >>= 1) sq += __shfl_xor(sq, m, 64);
    float inv = rsqrtf(sq * (1.f / 512.f) + 1e-5f);
    float4 lg0 = ((const float4*)(lg + cg * 8))[0];
    float4 lg1 = ((const float4*)(lg + cg * 8))[1];
    float4 lb0 = ((const float4*)(lb + cg * 8))[0];
    float4 lb1 = ((const float4*)(lb + cg * 8))[1];
    float lgv[8] = {lg0.x, lg0.y, lg0.z, lg0.w, lg1.x, lg1.y, lg1.z, lg1.w};
    float lbv[8] = {lb0.x, lb0.y, lb0.z, lb0.w, lb1.x, lb1.y, lb1.z, lb1.w};
    f16x8 hold = *(const f16x8*)&h16[(size_t)n * HID + cg * 8];
    f16x8 hnew;
#pragma unroll
    for (int j = 0; j < 8; ++j) {
        float r = d[j] * inv * lgv[j] + lbv[j] + (float)hold[j];
        hnew[j] = (_Float16)(r > 0.f ? r : 0.f);
    }
    if (esub == 0) *(f16x8*)&h16[(size_t)n * HID + cg * 8] = hnew;
}

// ================= per-graph pooling (h16) =================
__global__ void pool_graph_kernel(const _Float16* __restrict__ h16, const float* __restrict__ escore,
                                  const int* __restrict__ gstart, float* __restrict__ sums,
                                  float* __restrict__ cnts, float* __restrict__ hgZ, int G) {
    int g = blockIdx.x;
    int t = threadIdx.x;               // 0..511
    int c = t & 127, grp = t >> 7;     // 4 groups
    int s = gstart[g], e = gstart[g + 1];
    float msum = 0.f, asum = 0.f, z = 0.f;
    for (int n = s + grp; n < e; n += 4) {
        float hv = (float)h16[(size_t)n * HID + c];
        float es = escore[n];
        msum += hv;
        asum += es * hv;
        if (c == 0) z += es;
    }
    __shared__ float sm[4][HID];
    __shared__ float sa[4][HID];
    __shared__ float sz[4];
    sm[grp][c] = msum;
    sa[grp][c] = asum;
    if (c == 0) sz[grp] = z;
    __syncthreads();
    if (t < HID) {
        float m = sm[0][t] + sm[1][t] + sm[2][t] + sm[3][t];
        float a = sa[0][t] + sa[1][t] + sa[2][t] + sa[3][t];
        sums[(size_t)g * HID + t] = m;
        atomicAdd(&hgZ[t], a);
    } else if (t == HID) {
        cnts[g] = (float)(e - s);
        atomicAdd(&hgZ[HID], sz[0] + sz[1] + sz[2] + sz[3]);
    }
}

// ================= classifier head =================
__global__ void head_kernel(const float* __restrict__ hgZ, const float* __restrict__ sums,
                            const float* __restrict__ cnts, const float* __restrict__ W1,
                            const float* __restrict__ b1, const float* __restrict__ W2,
                            const float* __restrict__ b2, float* __restrict__ out, int G) {
    int g = blockIdx.x;
    int t = threadIdx.x;
    __shared__ float hr[HID];
    __shared__ float part[2];
    float Z = hgZ[HID];
    float cnt = cnts[g];
    cnt = cnt > 1.f ? cnt : 1.f;
    hr[t] = hgZ[t] / Z + sums[(size_t)g * HID + t] / cnt;
    __syncthreads();
    float acc = b1[t];
#pragma unroll 8
    for (int k = 0; k < HID; ++k) acc += hr[k] * W1[k * HID + t];
    acc = acc > 0.f ? acc : 0.f;
    float v = acc * W2[t];
#pragma unroll
    for (int m = 32; m >= 1; m >>= 1) v += __shfl_xor(v, m, 64);
    if ((t & 63) == 0) part[t >> 6] = v;
    __syncthreads();
    if (t == 0) out[g] = part[0] + part[1] + b2[0];
}

extern "C" void kernel_launch(void* const* d_in, const int* in_sizes, int n_in,
                              void* d_out, int out_size, void* d_ws, size_t ws_size,
                              hipStream_t stream) {
    const float* x        = (const float*)d_in[0];
    const int*   ei       = (const int*)d_in[1];
    const int*   ntypes   = (const int*)d_in[2];
    const int*   batch    = (const int*)d_in[3];
    const float* emb_W    = (const float*)d_in[4];
    const float* emb_b    = (const float*)d_in[5];
    const float* nemb     = (const float*)d_in[6];
    const float* gat_W    = (const float*)d_in[7];
    const float* att_src  = (const float*)d_in[8];
    const float* att_dst  = (const float*)d_in[9];
    const float* gat_b    = (const float*)d_in[10];
    const float* ln_g     = (const float*)d_in[11];
    const float* ln_b     = (const float*)d_in[12];
    const float* ga_W1    = (const float*)d_in[13];
    const float* ga_b1    = (const float*)d_in[14];
    const float* ga_W2    = (const float*)d_in[15];
    const float* ga_b2    = (const float*)d_in[16];
    const float* cls_W1   = (const float*)d_in[17];
    const float* cls_b1   = (const float*)d_in[18];
    const float* cls_W2   = (const float*)d_in[19];
    const float* cls_b2   = (const float*)d_in[20];
    float* out = (float*)d_out;

    const int N  = in_sizes[2];
    const int E  = in_sizes[1] / 2;
    const int EE = E + N;
    const int G  = out_size;
    const int NB = (N + 255) / 256;
    const int XT4 = N * INDIM / 4;

    float* ws      = (float*)d_ws;
    float* als     = ws;                               // N*8
    float* ald     = als + (size_t)N * HEADS;          // N*8
    float* escore  = ald + (size_t)N * HEADS;          // N
    float* sums    = escore + N;                       // G*128
    float* cnts    = sums + (size_t)G * HID;           // G
    float* hgZ     = cnts + G;                         // 129
    _Float16* h16  = (_Float16*)(hgZ + HID + 1);       // N*128
    _Float16* hp16 = h16 + (size_t)N * HID;            // N*128
    _Float16* x16  = hp16 + (size_t)N * HID;           // N*64
    _Float16* wt_emb = x16 + (size_t)N * INDIM;        // 128*64
    _Float16* wt_gat = wt_emb + 128 * 64;              // 3*128*128
    _Float16* wt_ga1 = wt_gat + 3 * 128 * 128;         // 128*128
    int*   rowptr  = (int*)(wt_ga1 + 128 * 128);       // N+1
    int*   woff    = rowptr + (N + 1);                 // N
    int*   deg     = woff + N;                         // N
    int*   esrc    = deg + N;                          // EE
    int*   partials= esrc + EE;                        // NB
    int*   gstart  = partials + NB;                    // G+1

    // ---- prologue: deg zero, then fused count/converts/gstart/hgZ-zero ----
    hipMemsetAsync(deg, 0, (size_t)N * sizeof(int), stream);
    int ptot = XT4 > EE ? XT4 : EE;
    if (ptot < 100000 + G + 1) ptot = 100000 + G + 1;
    prologue_kernel<<<(ptot + 255) / 256, 256, 0, stream>>>(
        ei, deg, x, x16, emb_W, gat_W, ga_W1, wt_emb, wt_gat, wt_ga1,
        batch, gstart, hgZ, E, EE, N, G, XT4);
    block_sum_kernel<<<NB, 256, 0, stream>>>(deg, partials, N);
    rowptr_kernel<<<NB, 256, 0, stream>>>(deg, partials, rowptr, woff, N, EE);
    scatter_kernel<<<(EE + 255) / 256, 256, 0, stream>>>(ei, woff, esrc, E, EE);

    const int PB = (N + 127) / 128;   // 2 tiles of 64 per block

    // ---- network ----
    mfma_proj_kernel<<<PB, 256, 0, stream>>>(
        0, INDIM, N, x16, wt_emb, emb_b, nemb, ntypes, h16,
        nullptr, nullptr, nullptr, nullptr, nullptr, nullptr, nullptr, nullptr);

    for (int l = 0; l < 3; ++l) {
        mfma_proj_kernel<<<PB, 256, 0, stream>>>(
            1, HID, N, h16, wt_gat + (size_t)l * HID * HID,
            nullptr, nullptr, nullptr, nullptr,
            att_src + l * HID, att_dst + l * HID,
            hp16, als, ald, nullptr, nullptr, nullptr);
        gat_aggregate_kernel<<<(N + 3) / 4, 256, 0, stream>>>(
            rowptr, esrc, als, ald, hp16,
            gat_b + l * HID, ln_g + l * HID, ln_b + l * HID, h16, N);
    }

    mfma_proj_kernel<<<PB, 256, 0, stream>>>(
        2, HID, N, h16, wt_ga1, ga_b1, nullptr, nullptr, nullptr,
        nullptr, nullptr, nullptr, nullptr, nullptr, ga_W2, ga_b2, escore);

    pool_graph_kernel<<<G, 512, 0, stream>>>(h16, escore, gstart, sums, cnts, hgZ, G);
    head_kernel<<<G, 128, 0, stream>>>(hgZ, sums, cnts, cls_W1, cls_b1, cls_W2, cls_b2, out, G);
}